// Round 1
// baseline (285.271 us; speedup 1.0000x reference)
//
#include <hip/hip_runtime.h>

// Problem constants (from reference):
//   N_SLICES=24, B=16, C=512, H=W=16 (HW=256), FEAT_IN=1024, CLASSES=3
// feat_o[b,c] == max_n mean_hw(oct_maps[n,b,c,:,:])  (argmax+gather+mean == max of means)

#define NS 24
#define BDIM 16
#define CDIM 512
#define HW 256
#define BC (BDIM * CDIM)   // 8192

// Kernel 1: one wave (64 lanes) per (b,c). Each wave reduces the 256-float
// feat_f segment and the 24 oct segments (each contiguous 1 KB, float4/lane).
__global__ __launch_bounds__(256) void reduce_feat_kernel(
    const float* __restrict__ feat_f_map,   // [B][C][HW]
    const float* __restrict__ oct,          // [NS][B][C][HW]
    float* __restrict__ feat)               // [B][1024]  (ws)
{
    const int wave = threadIdx.x >> 6;
    const int lane = threadIdx.x & 63;
    const int bc   = blockIdx.x * 4 + wave;   // 0..8191
    const int b    = bc >> 9;
    const int c    = bc & 511;

    // ---- feat_f: mean of 256 contiguous floats ----
    const float4* pf = reinterpret_cast<const float4*>(feat_f_map + (size_t)bc * HW);
    float4 v = pf[lane];
    float s = (v.x + v.y) + (v.z + v.w);
    #pragma unroll
    for (int off = 32; off; off >>= 1) s += __shfl_down(s, off);   // result on lane 0

    // ---- feat_o: max over slices of per-slice mean ----
    float mx = -3.4e38f;
    #pragma unroll 4
    for (int n = 0; n < NS; ++n) {
        const float4* po = reinterpret_cast<const float4*>(oct + ((size_t)n * BC + bc) * HW);
        float4 w = po[lane];
        float t = (w.x + w.y) + (w.z + w.w);
        #pragma unroll
        for (int off = 32; off; off >>= 1) t += __shfl_down(t, off);
        mx = fmaxf(mx, t);   // meaningful on lane 0 only
    }

    if (lane == 0) {
        feat[b * 1024 + c]       = s  * (1.0f / 256.0f);
        feat[b * 1024 + 512 + c] = mx * (1.0f / 256.0f);
    }
}

// Kernel 2: labels[b][k] = dot(feat[b], head_w[k]) + head_b[k]
// 48 outputs; one wave per output.
__global__ __launch_bounds__(64) void head_kernel(
    const float* __restrict__ feat,     // [B][1024]
    const float* __restrict__ head_w,   // [3][1024]
    const float* __restrict__ head_b,   // [3]
    float* __restrict__ out)            // [B][3]
{
    const int j = blockIdx.x;           // 0..47
    const int b = j / 3;
    const int k = j % 3;
    const int lane = threadIdx.x;

    const float* f = feat + b * 1024;
    const float* w = head_w + k * 1024;

    float s = 0.0f;
    #pragma unroll
    for (int i = 0; i < 1024 / 64; ++i)
        s += f[lane + i * 64] * w[lane + i * 64];

    #pragma unroll
    for (int off = 32; off; off >>= 1) s += __shfl_down(s, off);

    if (lane == 0) out[b * 3 + k] = s + head_b[k];
}

extern "C" void kernel_launch(void* const* d_in, const int* in_sizes, int n_in,
                              void* d_out, int out_size, void* d_ws, size_t ws_size,
                              hipStream_t stream) {
    const float* feat_f_map = (const float*)d_in[0];   // 16*512*256
    const float* oct        = (const float*)d_in[1];   // 24*16*512*256
    const float* head_w     = (const float*)d_in[2];   // 3*1024
    const float* head_b     = (const float*)d_in[3];   // 3
    float* out  = (float*)d_out;                       // 48
    float* feat = (float*)d_ws;                        // 16*1024 floats = 64 KB scratch

    // 8192 (b,c) pairs, 4 waves (one per pair) per 256-thread block.
    reduce_feat_kernel<<<BC / 4, 256, 0, stream>>>(feat_f_map, oct, feat);
    head_kernel<<<48, 64, 0, stream>>>(feat, head_w, head_b, out);
}